// Round 1
// 91.056 us; speedup vs baseline: 1.0519x; 1.0519x over previous
//
#include <hip/hip_runtime.h>

#define DEVINL __device__ __forceinline__

// ---------------------------------------------------------------------------
// Compile-time circuit constants via GF(2) linear-map tracking.
// Physical index p (10 bits): bits 9..4 = lane (6 bits), bits 3..0 = reg (4).
// Logical amplitude index a = A * p (A over GF(2)).  CNOT(c,t) => A row update
// with NO data movement.  A 1q gate on wire w pairs p with p ^ (A^{-1} e_{9-w});
// side bit = parity(row_{9-w}(A) & p).
//
// This round (VALU-issue-bound: VALUBusy 89%, MfmaUtil 0, HBM 0.35%):
//  * Layer-1 Rot = RZ(om)*RY(th)*RZ(phi).  RZ(om) dropped: only basis
//    permutations + |.|^2 follow it, so probabilities are invariant.
//  * All ten layer-1 RZ(phi) are diagonal -> commuted to state construction
//    and folded in closed form using the nibble structure of their rows:
//      w=1..5 (row&15==0): pure lane phase E_A -> into the lane factor
//      w=6 (mask 8), w=7 (mask 12): folded into t23 (P/Q pair + conj)
//      w=8 (14) + w0*w9 (15): chi14*chi15 = chi1 -> per-amp factor
//                             G(r) in {G0, G1, conj} picked at compile time
//  * Remaining layer-1 gates are REAL RY -> fast-Givens: new = a +- t*b with
//    t = tan(th/2) (one v_fmac per value); global scale prod cos(th/2) folded
//    into the lane factor once.  (th ~ 0.01 scale -> tan is benign; exact.)
//  * Expvals via 16-point Walsh-Hadamard (64 adds for all sign-sums).
//  * All cross-lane xors on the LDS pipe (ds_swizzle/bpermute), none on DPP:
//    the VALU pipe is the bottleneck, the LDS pipe is nearly idle.
// ---------------------------------------------------------------------------
struct GC { int laneXor, regXor, rowL, rowR; };
struct Circ { GC g[20]; int sgnL[10], sgnR[10]; };

constexpr Circ build_circ() {
    Circ c{};
    unsigned A[10] = {};
    for (int i = 0; i < 10; ++i) A[i] = 1u << i;
    // layer 0 Rot gates (A = I): mask = row = e_{9-w}  (unused at runtime)
    for (int w = 0; w < 10; ++w) {
        int pos = 9 - w;
        unsigned m = 1u << pos;
        c.g[w] = GC{ int(m >> 4), int(m & 15u), int(m >> 4), int(m & 15u) };
    }
    // layer 0 CNOT ring, range r=1
    for (int q = 0; q < 10; ++q) { int pc = 9 - q, pt = 9 - ((q + 1) % 10); A[pt] ^= A[pc]; }
    // invert A over GF(2)
    unsigned M[10] = {}, Inv[10] = {};
    for (int i = 0; i < 10; ++i) { M[i] = A[i]; Inv[i] = 1u << i; }
    for (int col = 0; col < 10; ++col) {
        int piv = col;
        while (!((M[piv] >> col) & 1u)) ++piv;
        unsigned tm = M[col]; M[col] = M[piv]; M[piv] = tm;
        unsigned ti = Inv[col]; Inv[col] = Inv[piv]; Inv[piv] = ti;
        for (int r = 0; r < 10; ++r)
            if (r != col && ((M[r] >> col) & 1u)) { M[r] ^= M[col]; Inv[r] ^= Inv[col]; }
    }
    // layer 1 Rot gates: m = A^{-1} e_pos, row = A[pos]
    for (int w = 0; w < 10; ++w) {
        int pos = 9 - w;
        unsigned m = 0;
        for (int i = 0; i < 10; ++i) m |= ((Inv[i] >> pos) & 1u) << i;
        unsigned row = A[pos];
        c.g[10 + w] = GC{ int(m >> 4), int(m & 15u), int(row >> 4), int(row & 15u) };
    }
    // layer 1 CNOT ring, range r=2
    for (int q = 0; q < 10; ++q) { int pc = 9 - q, pt = 9 - ((q + 2) % 10); A[pt] ^= A[pc]; }
    // output Z-sign parities
    for (int q = 0; q < 10; ++q) { unsigned row = A[9 - q]; c.sgnL[q] = int(row >> 4); c.sgnR[q] = int(row & 15u); }
    return c;
}

constexpr Circ CC = build_circ();

// The hand-derived phase folding below relies on exactly these row values.
static_assert(CC.g[10].rowL == 31 && CC.g[10].rowR == 15, "w0 row");
static_assert(CC.g[11].rowL == 48 && CC.g[11].rowR == 0,  "w1 row");
static_assert(CC.g[12].rowL == 56 && CC.g[12].rowR == 0,  "w2 row");
static_assert(CC.g[13].rowL == 60 && CC.g[13].rowR == 0,  "w3 row");
static_assert(CC.g[14].rowL == 62 && CC.g[14].rowR == 0,  "w4 row");
static_assert(CC.g[15].rowL == 63 && CC.g[15].rowR == 0,  "w5 row");
static_assert(CC.g[16].rowL == 63 && CC.g[16].rowR == 8,  "w6 row");
static_assert(CC.g[17].rowL == 63 && CC.g[17].rowR == 12, "w7 row");
static_assert(CC.g[18].rowL == 63 && CC.g[18].rowR == 14, "w8 row");
static_assert(CC.g[19].rowL == 63 && CC.g[19].rowR == 15, "w9 row");

// sign-word xor: sw has the sign in bit 31 (or is 0)
DEVINL float csw(float v, int sw) {
    return __int_as_float(__float_as_int(v) ^ sw);
}

// lane-xor fetch: ds_swizzle for xor<32, bpermute otherwise (all LDS pipe)
template<int XOR>
DEVINL float lx(float v, int lane) {
    int x = __float_as_int(v);
    int r;
    if constexpr (XOR < 32) r = __builtin_amdgcn_ds_swizzle(x, 0x1F | (XOR << 10));
    else                    r = __builtin_amdgcn_ds_bpermute((lane ^ XOR) << 2, x);
    return __int_as_float(r);
}

// per-wire embedding factor: |0> --RY(x)--> --Rot(layer0)--> (a0, a1)
DEVINL void wf(const float* sm, float xw, int w,
               float& a0r, float& a0i, float& a1r, float& a1i) {
    float h = 0.5f * xw;
    float s = __sinf(h), c = __cosf(h);
    float m0 = sm[w * 4 + 0], m1 = sm[w * 4 + 1], m2 = sm[w * 4 + 2], m3 = sm[w * 4 + 3];
    a0r =  m0 * c + m2 * s;
    a0i =  m1 * c + m3 * s;
    a1r = -m2 * c + m0 * s;
    a1i =  m3 * c - m1 * s;
}

// Layer-1 RY gates as fast-Givens:  new = a + (side ? +t : -t) * b,
// side = parity(lane&rowL) ^ parity(r&rowR).  Global cos product pre-folded.
template<int G>
DEVINL void rygates(float (&ar)[16], float (&ai)[16], const float* sm, int lane,
                    const int (&sw)[10]) {
    if constexpr (G < 20) {
        constexpr GC gc = CC.g[G];
        constexpr int w = G - 10;
        float t  = sm[40 + w * 4 + 1];         // tan(th/2)
        float tt = csw(t, sw[w]);              // +t if parity(lane&rowL)==0 else -t
        float br_[16], bi_[16];
        if constexpr (gc.laneXor == 0) {
            #pragma unroll
            for (int r = 0; r < 16; ++r) { br_[r] = ar[r ^ gc.regXor]; bi_[r] = ai[r ^ gc.regXor]; }
        } else {
            #pragma unroll
            for (int r = 0; r < 16; ++r) {
                br_[r] = lx<gc.laneXor>(ar[r ^ gc.regXor], lane);
                bi_[r] = lx<gc.laneXor>(ai[r ^ gc.regXor], lane);
            }
        }
        #pragma unroll
        for (int r = 0; r < 16; ++r) {
            const bool sR = __builtin_popcount(unsigned(gc.rowR & r)) & 1;
            if (sR) { ar[r] = fmaf( tt, br_[r], ar[r]); ai[r] = fmaf( tt, bi_[r], ai[r]); }
            else    { ar[r] = fmaf(-tt, br_[r], ar[r]); ai[r] = fmaf(-tt, bi_[r], ai[r]); }
        }
        rygates<G + 1>(ar, ai, sm, lane, sw);
    }
}

__global__ __launch_bounds__(256) void qsim(const float* __restrict__ x,
                                            const float* __restrict__ qw,
                                            float* __restrict__ out, int B) {
    // sm[0..39]:  layer-0 Rot matrices (u00r,u00i,u01r,u01i); SU(2) completes rest
    // sm[40..79]: layer-1 per wire: cos(th/2), tan(th/2), cos(phi/2), -sin(phi/2)
    __shared__ float sm[80];
    {
        int g = threadIdx.x;
        if (g < 10) {
            float phi = qw[g * 3 + 0], th = qw[g * 3 + 1], om = qw[g * 3 + 2];
            float c = cosf(0.5f * th), s = sinf(0.5f * th);
            float apo = 0.5f * (phi + om), amo = 0.5f * (phi - om);
            sm[g * 4 + 0] =  cosf(apo) * c;
            sm[g * 4 + 1] = -sinf(apo) * c;
            sm[g * 4 + 2] = -cosf(amo) * s;
            sm[g * 4 + 3] = -sinf(amo) * s;
        } else if (g < 20) {
            int w = g - 10;
            float phi = qw[g * 3 + 0], th = qw[g * 3 + 1];
            float c = cosf(0.5f * th), s = sinf(0.5f * th);
            sm[40 + w * 4 + 0] = c;
            sm[40 + w * 4 + 1] = s / c;
            sm[40 + w * 4 + 2] = cosf(0.5f * phi);
            sm[40 + w * 4 + 3] = -sinf(0.5f * phi);
        }
    }
    __syncthreads();

    int lane = threadIdx.x & 63;
    int b = __builtin_amdgcn_readfirstlane(blockIdx.x * 4 + (threadIdx.x >> 6));
    if (b >= B) return;
    const float* xb = x + b * 10;

    // ---- lane-parity sign words for the layer-1 rows (bit 31 = sign)
    int l = lane;
    int p48 = (l >> 4) ^ (l >> 5);
    int p56 = p48 ^ (l >> 3);
    int p60 = p56 ^ (l >> 2);
    int p62 = p60 ^ (l >> 1);
    int p63 = p62 ^ l;
    int p31 = p63 ^ (l >> 5);
    int s48 = p48 << 31, s56 = p56 << 31, s60 = p60 << 31;
    int s62 = p62 << 31, s63 = p63 << 31, s31 = p31 << 31;
    int sw[10] = { s31, s48, s56, s60, s62, s63, s63, s63, s63, s63 };

    // ---- reg-wire factors -> t01 (wires 9,8 = reg bits 0,1), t23 (wires 7,6)
    float t01r[4], t01i[4], t23r[4], t23i[4];
    {
        float a0r, a0i, a1r, a1i, b0r, b0i, b1r, b1i;
        wf(sm, xb[9], 9, a0r, a0i, a1r, a1i);
        wf(sm, xb[8], 8, b0r, b0i, b1r, b1i);
        t01r[0] = a0r * b0r - a0i * b0i;  t01i[0] = a0r * b0i + a0i * b0r;
        t01r[1] = a1r * b0r - a1i * b0i;  t01i[1] = a1r * b0i + a1i * b0r;
        t01r[2] = a0r * b1r - a0i * b1i;  t01i[2] = a0r * b1i + a0i * b1r;
        t01r[3] = a1r * b1r - a1i * b1i;  t01i[3] = a1r * b1i + a1i * b1r;
        wf(sm, xb[7], 7, a0r, a0i, a1r, a1i);
        wf(sm, xb[6], 6, b0r, b0i, b1r, b1i);
        t23r[0] = a0r * b0r - a0i * b0i;  t23i[0] = a0r * b0i + a0i * b0r;
        t23r[1] = a1r * b0r - a1i * b0i;  t23i[1] = a1r * b0i + a1i * b0r;
        t23r[2] = a0r * b1r - a0i * b1i;  t23i[2] = a0r * b1i + a0i * b1r;
        t23r[3] = a1r * b1r - a1i * b1i;  t23i[3] = a1r * b1i + a1i * b1r;
    }

    // ---- lane factor: E_A (phases of w1..5) * RY cos-product * wire factors
    float lfr, lfi;
    {
        float ear = sm[40 + 1 * 4 + 2], eai = csw(sm[40 + 1 * 4 + 3], sw[1]);
        #pragma unroll
        for (int w = 2; w <= 5; ++w) {
            float er = sm[40 + w * 4 + 2], ei = csw(sm[40 + w * 4 + 3], sw[w]);
            float nr = ear * er - eai * ei;
            float ni = ear * ei + eai * er;
            ear = nr; eai = ni;
        }
        float sc = sm[40];
        #pragma unroll
        for (int w = 1; w < 10; ++w) sc *= sm[40 + w * 4];
        lfr = ear * sc; lfi = eai * sc;
        #pragma unroll
        for (int jj = 0; jj < 6; ++jj) {
            int w = 5 - jj;                       // lane bit jj <-> wire 5-jj
            float a0r, a0i, a1r, a1i;
            wf(sm, xb[w], w, a0r, a0i, a1r, a1i);
            int bit = (lane >> jj) & 1;
            float pr = bit ? a1r : a0r;
            float pi = bit ? a1i : a0i;
            float nr = lfr * pr - lfi * pi;
            float ni = lfr * pi + lfi * pr;
            lfr = nr; lfi = ni;
        }
    }

    // ---- fold w6/w7 phases into t23:  P = E6*E7, Q = E6*conj(E7)
    float e6r = sm[40 + 6 * 4 + 2], e6i = csw(sm[40 + 6 * 4 + 3], sw[6]);
    float e7r = sm[40 + 7 * 4 + 2], e7i = csw(sm[40 + 7 * 4 + 3], sw[7]);
    float Pr_ = e6r * e7r - e6i * e7i, Pi_ = e6r * e7i + e6i * e7r;
    float Qr_ = e6r * e7r + e6i * e7i, Qi_ = e6i * e7r - e6r * e7i;
    float t23pr[4], t23pi[4];
    // C(0)=P, C(1)=Q, C(2)=conj(P), C(3)=conj(Q)
    t23pr[0] = t23r[0] * Pr_ - t23i[0] * Pi_;  t23pi[0] = t23r[0] * Pi_ + t23i[0] * Pr_;
    t23pr[1] = t23r[1] * Qr_ - t23i[1] * Qi_;  t23pi[1] = t23r[1] * Qi_ + t23i[1] * Qr_;
    t23pr[2] = t23r[2] * Pr_ + t23i[2] * Pi_;  t23pi[2] = t23i[2] * Pr_ - t23r[2] * Pi_;
    t23pr[3] = t23r[3] * Qr_ + t23i[3] * Qi_;  t23pi[3] = t23i[3] * Qr_ - t23r[3] * Qi_;

    // ---- w8 + (w0*w9) phases:  G0 = E8*EB, G1 = E8*conj(EB), EB = E0*E9
    float e0r = sm[40 + 0 * 4 + 2], e0i = csw(sm[40 + 0 * 4 + 3], sw[0]);
    float e9r = sm[40 + 9 * 4 + 2], e9i = csw(sm[40 + 9 * 4 + 3], sw[9]);
    float e8r = sm[40 + 8 * 4 + 2], e8i = csw(sm[40 + 8 * 4 + 3], sw[8]);
    float ebr = e0r * e9r - e0i * e9i, ebi = e0r * e9i + e0i * e9r;
    float G0r = e8r * ebr - e8i * ebi, G0i = e8r * ebi + e8i * ebr;
    float G1r = e8r * ebr + e8i * ebi, G1i = e8i * ebr - e8r * ebi;

    // ---- g4 = lf * t01 ; amps = (g4 (x) t23p) * G(r)
    float g4r[4], g4i[4];
    #pragma unroll
    for (int v = 0; v < 4; ++v) {
        g4r[v] = lfr * t01r[v] - lfi * t01i[v];
        g4i[v] = lfr * t01i[v] + lfi * t01r[v];
    }
    float ar[16], ai[16];
    #pragma unroll
    for (int r = 0; r < 16; ++r) {
        float tr = g4r[r & 3] * t23pr[r >> 2] - g4i[r & 3] * t23pi[r >> 2];
        float ti = g4r[r & 3] * t23pi[r >> 2] + g4i[r & 3] * t23pr[r >> 2];
        float gr = (r & 1) ? G1r : G0r;                       // compile-time
        float gi = (r & 1) ? G1i : G0i;
        if (__builtin_popcount(unsigned(r & 14)) & 1) gi = -gi; // conj, compile-time
        ar[r] = tr * gr - ti * gi;
        ai[r] = tr * gi + ti * gr;
    }

    // ---- layer-1 RY gates (fast-Givens; CNOT rings folded into index algebra)
    rygates<10>(ar, ai, sm, lane, sw);

    // ---- probabilities + 16-point Walsh-Hadamard over the 4 reg bits
    float wv[16];
    #pragma unroll
    for (int r = 0; r < 16; ++r) wv[r] = ar[r] * ar[r] + ai[r] * ai[r];
    #pragma unroll
    for (int bS = 1; bS < 16; bS <<= 1) {
        #pragma unroll
        for (int r = 0; r < 16; ++r) {
            if (!(r & bS)) {
                float xv = wv[r], yv = wv[r | bS];
                wv[r]      = xv + yv;
                wv[r | bS] = xv - yv;
            }
        }
    }

    float e[10];
    #pragma unroll
    for (int q = 0; q < 10; ++q) {
        int slq = __popc(unsigned(lane & CC.sgnL[q])) & 1;
        e[q] = csw(wv[CC.sgnR[q]], slq << 31);
    }
    #pragma unroll
    for (int q = 0; q < 10; ++q) {
        e[q] += lx<1>(e[q], lane);
        e[q] += lx<2>(e[q], lane);
        e[q] += lx<4>(e[q], lane);
        e[q] += lx<8>(e[q], lane);
        e[q] += lx<16>(e[q], lane);
        e[q] += lx<32>(e[q], lane);
    }
    float v = e[0];
    #pragma unroll
    for (int q = 1; q < 10; ++q) v = (lane == q) ? e[q] : v;
    if (lane < 10) out[b * 10 + lane] = v;
}

extern "C" void kernel_launch(void* const* d_in, const int* in_sizes, int n_in,
                              void* d_out, int out_size, void* d_ws, size_t ws_size,
                              hipStream_t stream) {
    const float* x  = (const float*)d_in[0];
    const float* qw = (const float*)d_in[1];
    float* out = (float*)d_out;
    int B = in_sizes[0] / 10;
    int blocks = (B + 3) / 4;   // 4 samples (waves) per 256-thread block
    hipLaunchKernelGGL(qsim, dim3(blocks), dim3(256), 0, stream, x, qw, out, B);
}